// Round 9
// baseline (195.183 us; speedup 1.0000x reference)
//
#include <hip/hip_runtime.h>

// DIAGNOSTIC ROUND (R9): R8 structure with the main body repeated 8x, slice
// assignment rotated per rep (ns' = (ns+rep)&7) to defeat cross-rep CSE while
// keeping stores idempotent (same value for same (slice,b,col) from any rep).
// Purpose: main kernel has been invisible in top-5 behind the harness's fixed
// ~40us poison fills since R1; 8x amplification forces its counter row into
// top-5 so MfmaUtil/VALUBusy/Occupancy/FETCH/LDS_CONFLICT can adjudicate
// between latency-bound / VALU-bound / matrix-bound / spill theories.
// Next round reverts to the R8 two-dispatch kernel + the indicated fix.
//
// Math (unchanged, absmax=0 through R8): dist = oo_n + aa_m - 2 o.a via
// mfma_f32_32x32x16_f16 with fp16 hi/lo split packing, fp32 accumulate.

#define KPTS 8192
#define BATCH 8
#define NSPLIT 8
#define RBLK (KPTS / NSPLIT)          // 1024 rows per slice
#define TSLICE (RBLK / 32)            // 32 MFMA row-tiles per slice
#define CBLK 512                      // adv columns per block (4 waves x 128)
#define MCHUNK (KPTS / CBLK)          // 16
#define REPS 8                        // diagnostic amplification

typedef _Float16 half8 __attribute__((ext_vector_type(8)));
typedef float f32x16 __attribute__((ext_vector_type(16)));

__device__ __forceinline__ float min16acc(float rm, const f32x16 c) {
    float u0 = fminf(fminf(c[0],  c[1]),  c[2]);
    float u1 = fminf(fminf(c[3],  c[4]),  c[5]);
    float u2 = fminf(fminf(c[6],  c[7]),  c[8]);
    float u3 = fminf(fminf(c[9],  c[10]), c[11]);
    float u4 = fminf(fminf(c[12], c[13]), c[14]);
    float u5 = fminf(fminf(u0, u1), c[15]);
    float u6 = fminf(fminf(u2, u3), u4);
    return fminf(fminf(u5, u6), rm);
}

__global__ __launch_bounds__(256, 4) void hausdorff(const float* __restrict__ adv,
                                                    const float* __restrict__ ori,
                                                    float* __restrict__ part,
                                                    float* __restrict__ out) {
    __shared__ _Float16 sA[(TSLICE + 1) * 512];   // 33 KB, tile-planar

    const int bid  = blockIdx.x;          // grid = 8 * 16 * 8 = 1024
    const int b    = bid >> 7;
    const int mc   = (bid >> 3) & (MCHUNK - 1);
    const int ns   = bid & 7;
    const int tid  = threadIdx.x;
    const int lane = tid & 63;
    const int wv   = tid >> 6;
    const int r    = lane & 31;
    const int hk   = lane >> 5;

    if (bid == 0 && tid == 0) out[0] = 0.0f;

    const _Float16 Z = (_Float16)0.0f, ONE = (_Float16)1.0f;

    // ---- B-fragments + aa (per-block constant, hoisted out of reps) ----
    const float* advb = adv + (size_t)b * KPTS * 3;
    const int m0 = mc * CBLK + wv * 128 + r;
    half8 bf0, bf1, bf2, bf3;
    float aa0, aa1, aa2, aa3;
#pragma unroll
    for (int i = 0; i < 4; ++i) {
        const int m = m0 + 32 * i;
        float ax = advb[3 * m], ay = advb[3 * m + 1], az = advb[3 * m + 2];
        float aa = ax * ax + ay * ay + az * az;
        float tx = -2.f * ax, ty = -2.f * ay, tz = -2.f * az;
        _Float16 bx = (_Float16)tx, by = (_Float16)ty, bz = (_Float16)tz;
        _Float16 cx = (_Float16)(tx - (float)bx);
        _Float16 cy = (_Float16)(ty - (float)by);
        _Float16 cz = (_Float16)(tz - (float)bz);
        half8 h0 = {bx, by, bz, cx, cy, cz, bx, by};
        half8 h1 = {bz, ONE, ONE, Z, Z, Z, Z, Z};
        half8 bi = hk ? h1 : h0;
        if (i == 0) { bf0 = bi; aa0 = aa; }
        else if (i == 1) { bf1 = bi; aa1 = aa; }
        else if (i == 2) { bf2 = bi; aa2 = aa; }
        else { bf3 = bi; aa3 = aa; }
    }

    f32x16 zc;
#pragma unroll
    for (int i = 0; i < 16; ++i) zc[i] = 0.0f;

#pragma unroll 1
    for (int rep = 0; rep < REPS; ++rep) {
        const int ns2 = (ns + rep) & 7;    // rotate slice: defeats cross-rep CSE

        __syncthreads();   // previous rep's readers done before restaging

        // ---- stage + convert this rep's 1024-row slice into LDS ----
        const float* orib = ori + ((size_t)b * KPTS + (size_t)ns2 * RBLK) * 3;
#pragma unroll
        for (int i = 0; i < 4; ++i) {
            const int rr = tid + i * 256;
            const float* op = orib + (size_t)rr * 3;
            float x = op[0], y = op[1], z = op[2];
            float oo = x * x + y * y + z * z;
            _Float16 hx = (_Float16)x, hy = (_Float16)y, hz = (_Float16)z;
            _Float16 lx = (_Float16)(x - (float)hx);
            _Float16 ly = (_Float16)(y - (float)hy);
            _Float16 lz = (_Float16)(z - (float)hz);
            _Float16 oh = (_Float16)oo;
            _Float16 ol = (_Float16)(oo - (float)oh);
            half8 a0 = {hx, hy, hz, hx, hy, hz, lx, ly};
            half8 a1 = {lz, oh, ol, Z, Z, Z, Z, Z};
            const int off = ((rr >> 5) << 9) + ((rr & 31) << 3);
            *(half8*)(&sA[off])       = a0;
            *(half8*)(&sA[off + 256]) = a1;
        }
        __syncthreads();

        float rm0 = __builtin_huge_valf(), rm1 = __builtin_huge_valf();
        float rm2 = __builtin_huge_valf(), rm3 = __builtin_huge_valf();

        const _Float16* apl = sA + lane * 8;
        half8 af = *(const half8*)apl;

#pragma unroll 2
        for (int t = 0; t < TSLICE; ++t) {
            half8 afn = *(const half8*)(apl + (size_t)(t + 1) * 512);

            f32x16 d0, d1;
            asm("v_mfma_f32_32x32x16_f16 %0, %2, %3, %5\n\t"
                "v_mfma_f32_32x32x16_f16 %1, %2, %4, %5\n\t"
                "s_nop 7\n\ts_nop 7\n\ts_nop 7"
                : "=&v"(d0), "=&v"(d1)
                : "v"(af), "v"(bf0), "v"(bf1), "v"(zc));
            rm0 = min16acc(rm0, d0);
            rm1 = min16acc(rm1, d1);

            f32x16 d2, d3;
            asm("v_mfma_f32_32x32x16_f16 %0, %2, %3, %5\n\t"
                "v_mfma_f32_32x32x16_f16 %1, %2, %4, %5\n\t"
                "s_nop 7\n\ts_nop 7\n\ts_nop 7"
                : "=&v"(d2), "=&v"(d3)
                : "v"(af), "v"(bf2), "v"(bf3), "v"(zc));
            rm2 = min16acc(rm2, d2);
            rm3 = min16acc(rm3, d3);

            af = afn;
        }

        rm0 = fminf(rm0, __shfl_xor(rm0, 32, 64));
        rm1 = fminf(rm1, __shfl_xor(rm1, 32, 64));
        rm2 = fminf(rm2, __shfl_xor(rm2, 32, 64));
        rm3 = fminf(rm3, __shfl_xor(rm3, 32, 64));

        // idempotent: value for (ns2,b,col) identical from any rep/block
        float* p = part + ((size_t)ns2 * BATCH + b) * KPTS;
        if (hk == 0) {
            p[m0]      = fmaxf(rm0 + aa0, 0.0f);
            p[m0 + 32] = fmaxf(rm1 + aa1, 0.0f);
            p[m0 + 64] = fmaxf(rm2 + aa2, 0.0f);
            p[m0 + 96] = fmaxf(rm3 + aa3, 0.0f);
        }
    }
}

// 8 blocks (one per batch), 1024 threads: min over slices, max over columns.
__global__ __launch_bounds__(1024) void reduceB(const float* __restrict__ part,
                                                const float* __restrict__ w,
                                                float* __restrict__ out) {
    const int b = blockIdx.x;
    const int tid = threadIdx.x;

    float mx = 0.0f;
#pragma unroll
    for (int h = 0; h < 2; ++h) {
        const int c4 = tid + h * 1024;
        float4 v[NSPLIT];
#pragma unroll
        for (int s = 0; s < NSPLIT; ++s)
            v[s] = *(const float4*)(part + ((size_t)s * BATCH + b) * KPTS + (size_t)c4 * 4);
        float4 mn = v[0];
#pragma unroll
        for (int s = 1; s < NSPLIT; ++s) {
            mn.x = fminf(mn.x, v[s].x); mn.y = fminf(mn.y, v[s].y);
            mn.z = fminf(mn.z, v[s].z); mn.w = fminf(mn.w, v[s].w);
        }
        mx = fmaxf(mx, fmaxf(fmaxf(mn.x, mn.y), fmaxf(mn.z, mn.w)));
    }

#pragma unroll
    for (int off = 32; off; off >>= 1)
        mx = fmaxf(mx, __shfl_xor(mx, off, 64));

    __shared__ float red[16];
    if ((tid & 63) == 0) red[tid >> 6] = mx;
    __syncthreads();
    if (tid == 0) {
        float m2 = red[0];
#pragma unroll
        for (int i = 1; i < 16; ++i) m2 = fmaxf(m2, red[i]);
        atomicAdd(out, m2 * w[b] * (1.0f / BATCH));
    }
}

extern "C" void kernel_launch(void* const* d_in, const int* in_sizes, int n_in,
                              void* d_out, int out_size, void* d_ws, size_t ws_size,
                              hipStream_t stream) {
    const float* adv = (const float*)d_in[0];   // [B, K, 3]
    const float* ori = (const float*)d_in[1];   // [B, K, 3]
    const float* w   = (const float*)d_in[2];   // [B]
    float* out = (float*)d_out;
    float* part = (float*)d_ws;                 // NSPLIT*B*K floats = 2 MB

    hausdorff<<<BATCH * MCHUNK * NSPLIT, 256, 0, stream>>>(adv, ori, part, out);
    reduceB<<<BATCH, 1024, 0, stream>>>((const float*)part, w, out);
}

// Round 10
// 77.386 us; speedup vs baseline: 2.5222x; 2.5222x over previous
//
#include <hip/hip_runtime.h>

// Hausdorff adv2ori via MFMA: B=8, K=8192.
// dist(n,m) = oo_n + aa_m - 2*o.a ; C = mfma(A',B') = oo_n - 2*o.a (fp16 hi/lo split)
// loss = mean_b( w_b * max_m min_n dist )
//
// R9 diagnostic (8x amplified, counters visible): per-rep main 18.7us,
// MfmaUtil 42%, VALUBusy 59%, conflicts 0, no spills. Verdict: VALU-issue
// bound by the scalar fminf fold (16 v_min x 2cyc = 32cyc/MFMA vs 8cyc matrix)
// plus aligned s_nop stall windows (6x s_nop7 per tile).
// R10: (a) v_min3_f32 fold forced via asm: 17->1 in 8 ops (optimal);
//      (b) one 4-MFMA asm block + 2 s_nop7; d0 covered by 3 MFMA issues+16cyc,
//          d1..d3 covered by preceding folds. Stall 48->16 cyc/tile.
// Structure otherwise = R8 (passed, absmax=0): tile-planar LDS slice, one
// barrier, plain-store partials, reduceB second dispatch.

#define KPTS 8192
#define BATCH 8
#define NSPLIT 8
#define RBLK (KPTS / NSPLIT)          // 1024 rows per slice
#define TSLICE (RBLK / 32)            // 32 MFMA row-tiles per slice
#define CBLK 512                      // adv columns per block (4 waves x 128)
#define MCHUNK (KPTS / CBLK)          // 16

typedef _Float16 half8 __attribute__((ext_vector_type(8)));
typedef float f32x16 __attribute__((ext_vector_type(16)));

// min(rm, c[0..15]) in exactly 8 v_min3_f32 (3-ary tree over 17 leaves).
__device__ __forceinline__ float min17_asm(float rm, const f32x16 c) {
    float t0, t1, t2, t3, t4, t5, t6, out;
    asm("v_min3_f32 %0, %8, %9, %10\n\t"     // t0 = c0,c1,c2
        "v_min3_f32 %1, %11, %12, %13\n\t"   // t1 = c3,c4,c5
        "v_min3_f32 %2, %14, %15, %16\n\t"   // t2 = c6,c7,c8
        "v_min3_f32 %3, %17, %18, %19\n\t"   // t3 = c9,c10,c11
        "v_min3_f32 %4, %20, %21, %22\n\t"   // t4 = c12,c13,c14
        "v_min3_f32 %5, %23, %24, %0\n\t"    // t5 = c15,rm,t0
        "v_min3_f32 %6, %1, %2, %3\n\t"      // t6 = t1,t2,t3
        "v_min3_f32 %7, %4, %5, %6"          // out = t4,t5,t6
        : "=&v"(t0), "=&v"(t1), "=&v"(t2), "=&v"(t3), "=&v"(t4),
          "=&v"(t5), "=v"(t6), "=v"(out)
        : "v"(c[0]), "v"(c[1]), "v"(c[2]), "v"(c[3]), "v"(c[4]), "v"(c[5]),
          "v"(c[6]), "v"(c[7]), "v"(c[8]), "v"(c[9]), "v"(c[10]), "v"(c[11]),
          "v"(c[12]), "v"(c[13]), "v"(c[14]), "v"(c[15]), "v"(rm));
    return out;
}

__global__ __launch_bounds__(256, 4) void hausdorff(const float* __restrict__ adv,
                                                    const float* __restrict__ ori,
                                                    float* __restrict__ part,
                                                    float* __restrict__ out) {
    // Tile-planar A' slice: tile t at halfs [t*512,(t+1)*512); lane reads
    // byte lane*16 -> linear, conflict-free. +1 pad tile for last prefetch.
    __shared__ _Float16 sA[(TSLICE + 1) * 512];   // 33 KB -> 4 blocks/CU

    const int bid  = blockIdx.x;          // grid = 8 * 16 * 8 = 1024
    const int b    = bid >> 7;
    const int mc   = (bid >> 3) & (MCHUNK - 1);
    const int ns   = bid & 7;
    const int tid  = threadIdx.x;
    const int lane = tid & 63;
    const int wv   = tid >> 6;
    const int r    = lane & 31;
    const int hk   = lane >> 5;

    if (bid == 0 && tid == 0) out[0] = 0.0f;   // for reduceB's atomicAdd

    const _Float16 Z = (_Float16)0.0f, ONE = (_Float16)1.0f;

    // ---- B-fragments + aa for this wave's 4 column groups ----
    const float* advb = adv + (size_t)b * KPTS * 3;
    const int m0 = mc * CBLK + wv * 128 + r;
    half8 bf0, bf1, bf2, bf3;
    float aa0, aa1, aa2, aa3;
#pragma unroll
    for (int i = 0; i < 4; ++i) {
        const int m = m0 + 32 * i;
        float ax = advb[3 * m], ay = advb[3 * m + 1], az = advb[3 * m + 2];
        float aa = ax * ax + ay * ay + az * az;
        float tx = -2.f * ax, ty = -2.f * ay, tz = -2.f * az;
        _Float16 bx = (_Float16)tx, by = (_Float16)ty, bz = (_Float16)tz;
        _Float16 cx = (_Float16)(tx - (float)bx);
        _Float16 cy = (_Float16)(ty - (float)by);
        _Float16 cz = (_Float16)(tz - (float)bz);
        half8 h0 = {bx, by, bz, cx, cy, cz, bx, by};
        half8 h1 = {bz, ONE, ONE, Z, Z, Z, Z, Z};
        half8 bi = hk ? h1 : h0;
        if (i == 0) { bf0 = bi; aa0 = aa; }
        else if (i == 1) { bf1 = bi; aa1 = aa; }
        else if (i == 2) { bf2 = bi; aa2 = aa; }
        else { bf3 = bi; aa3 = aa; }
    }

    // ---- stage + convert this block's 1024-row slice into LDS (once) ----
    const float* orib = ori + ((size_t)b * KPTS + (size_t)ns * RBLK) * 3;
#pragma unroll
    for (int i = 0; i < 4; ++i) {
        const int rr = tid + i * 256;
        const float* op = orib + (size_t)rr * 3;
        float x = op[0], y = op[1], z = op[2];
        float oo = x * x + y * y + z * z;
        _Float16 hx = (_Float16)x, hy = (_Float16)y, hz = (_Float16)z;
        _Float16 lx = (_Float16)(x - (float)hx);
        _Float16 ly = (_Float16)(y - (float)hy);
        _Float16 lz = (_Float16)(z - (float)hz);
        _Float16 oh = (_Float16)oo;
        _Float16 ol = (_Float16)(oo - (float)oh);
        half8 a0 = {hx, hy, hz, hx, hy, hz, lx, ly};
        half8 a1 = {lz, oh, ol, Z, Z, Z, Z, Z};
        const int off = ((rr >> 5) << 9) + ((rr & 31) << 3);
        *(half8*)(&sA[off])       = a0;
        *(half8*)(&sA[off + 256]) = a1;
    }
    __syncthreads();   // the only barrier

    f32x16 zc;
#pragma unroll
    for (int i = 0; i < 16; ++i) zc[i] = 0.0f;

    float rm0 = __builtin_huge_valf(), rm1 = __builtin_huge_valf();
    float rm2 = __builtin_huge_valf(), rm3 = __builtin_huge_valf();

    const _Float16* apl = sA + lane * 8;   // lane's 16B within tile 0
    half8 af = *(const half8*)apl;

#pragma unroll 2
    for (int t = 0; t < TSLICE; ++t) {
        half8 afn = *(const half8*)(apl + (size_t)(t + 1) * 512);  // prefetch (pad at t=31)

        // 4 MFMAs, one block; d0's first VALU read sits behind 3 MFMA issues
        // + 16 nop-cycles (>= ~18 wait states); d1..d3 behind 8+ fold ops each.
        f32x16 d0, d1, d2, d3;
        asm("v_mfma_f32_32x32x16_f16 %0, %4, %5, %9\n\t"
            "v_mfma_f32_32x32x16_f16 %1, %4, %6, %9\n\t"
            "v_mfma_f32_32x32x16_f16 %2, %4, %7, %9\n\t"
            "v_mfma_f32_32x32x16_f16 %3, %4, %8, %9\n\t"
            "s_nop 7\n\ts_nop 7"
            : "=&v"(d0), "=&v"(d1), "=&v"(d2), "=&v"(d3)
            : "v"(af), "v"(bf0), "v"(bf1), "v"(bf2), "v"(bf3), "v"(zc));

        rm0 = min17_asm(rm0, d0);
        rm1 = min17_asm(rm1, d1);
        rm2 = min17_asm(rm2, d2);
        rm3 = min17_asm(rm3, d3);

        af = afn;
    }

    // complete the 32-row min (lanes l, l^32 cover complementary rows, same col)
    rm0 = fminf(rm0, __shfl_xor(rm0, 32, 64));
    rm1 = fminf(rm1, __shfl_xor(rm1, 32, 64));
    rm2 = fminf(rm2, __shfl_xor(rm2, 32, 64));
    rm3 = fminf(rm3, __shfl_xor(rm3, 32, 64));

    // plain coalesced partial stores part[ns][b][col] (no init required)
    float* p = part + ((size_t)ns * BATCH + b) * KPTS;
    if (hk == 0) {
        p[m0]      = fmaxf(rm0 + aa0, 0.0f);
        p[m0 + 32] = fmaxf(rm1 + aa1, 0.0f);
        p[m0 + 64] = fmaxf(rm2 + aa2, 0.0f);
        p[m0 + 96] = fmaxf(rm3 + aa3, 0.0f);
    }
}

// 8 blocks (one per batch), 1024 threads: min over slices, max over columns.
__global__ __launch_bounds__(1024) void reduceB(const float* __restrict__ part,
                                                const float* __restrict__ w,
                                                float* __restrict__ out) {
    const int b = blockIdx.x;
    const int tid = threadIdx.x;

    float mx = 0.0f;   // partials are clamped nonneg
#pragma unroll
    for (int h = 0; h < 2; ++h) {
        const int c4 = tid + h * 1024;
        float4 v[NSPLIT];
#pragma unroll
        for (int s = 0; s < NSPLIT; ++s)
            v[s] = *(const float4*)(part + ((size_t)s * BATCH + b) * KPTS + (size_t)c4 * 4);
        float4 mn = v[0];
#pragma unroll
        for (int s = 1; s < NSPLIT; ++s) {
            mn.x = fminf(mn.x, v[s].x); mn.y = fminf(mn.y, v[s].y);
            mn.z = fminf(mn.z, v[s].z); mn.w = fminf(mn.w, v[s].w);
        }
        mx = fmaxf(mx, fmaxf(fmaxf(mn.x, mn.y), fmaxf(mn.z, mn.w)));
    }

#pragma unroll
    for (int off = 32; off; off >>= 1)
        mx = fmaxf(mx, __shfl_xor(mx, off, 64));

    __shared__ float red[16];
    if ((tid & 63) == 0) red[tid >> 6] = mx;
    __syncthreads();
    if (tid == 0) {
        float m2 = red[0];
#pragma unroll
        for (int i = 1; i < 16; ++i) m2 = fmaxf(m2, red[i]);
        atomicAdd(out, m2 * w[b] * (1.0f / BATCH));
    }
}

extern "C" void kernel_launch(void* const* d_in, const int* in_sizes, int n_in,
                              void* d_out, int out_size, void* d_ws, size_t ws_size,
                              hipStream_t stream) {
    const float* adv = (const float*)d_in[0];   // [B, K, 3]
    const float* ori = (const float*)d_in[1];   // [B, K, 3]
    const float* w   = (const float*)d_in[2];   // [B]
    float* out = (float*)d_out;
    float* part = (float*)d_ws;                 // NSPLIT*B*K floats = 2 MB

    hausdorff<<<BATCH * MCHUNK * NSPLIT, 256, 0, stream>>>(adv, ori, part, out);
    reduceB<<<BATCH, 1024, 0, stream>>>((const float*)part, w, out);
}

// Round 11
// 77.110 us; speedup vs baseline: 2.5312x; 1.0036x over previous
//
#include <hip/hip_runtime.h>

// Hausdorff adv2ori via MFMA: B=8, K=8192.
// dist(n,m) = oo_n + aa_m - 2*o.a ; C = mfma(A',B') = oo_n - 2*o.a (fp16 hi/lo split)
// loss = mean_b( w_b * max_m min_n dist )
//
// R10 post-mortem: 77.4us total; main ~15us. R9 counters: matrix busy 7.9us,
// VALU busy 11us, but the loop is serial per wave {4 MFMA, s_nop, 32 min3} ->
// pipes alternate instead of overlap (measured ~= serial sum).
// R11: 1-deep software pipeline in asm: {fold01(t-1), MFMA01(t), fold23(t-1),
// MFMA23(t)}. Every MFMA's first read is ~22+ instrs later (RAW wait states
// covered by useful fold work) -> zero s_nops in loop; matrix and VALU pipes
// overlap. WAR (MFMA overwrites just-folded d) safe under in-order issue.
// All asm volatile to pin the interleave. Regs ~120 -> (256,4) single round.

#define KPTS 8192
#define BATCH 8
#define NSPLIT 8
#define RBLK (KPTS / NSPLIT)          // 1024 rows per slice
#define TSLICE (RBLK / 32)            // 32 MFMA row-tiles per slice
#define CBLK 512                      // adv columns per block (4 waves x 128)
#define MCHUNK (KPTS / CBLK)          // 16

typedef _Float16 half8 __attribute__((ext_vector_type(8)));
typedef float f32x16 __attribute__((ext_vector_type(16)));

// rm = min(rm, c[0..15]) in exactly 8 v_min3_f32 (3-ary tree over 17 leaves).
#define FOLD17(rm, c)                                                         \
    do {                                                                      \
        float t0_, t1_, t2_, t3_, t4_, t5_, t6_, o_;                          \
        asm volatile(                                                         \
            "v_min3_f32 %0, %8, %9, %10\n\t"                                  \
            "v_min3_f32 %1, %11, %12, %13\n\t"                                \
            "v_min3_f32 %2, %14, %15, %16\n\t"                                \
            "v_min3_f32 %3, %17, %18, %19\n\t"                                \
            "v_min3_f32 %4, %20, %21, %22\n\t"                                \
            "v_min3_f32 %5, %23, %24, %0\n\t"                                 \
            "v_min3_f32 %6, %1, %2, %3\n\t"                                   \
            "v_min3_f32 %7, %4, %5, %6"                                       \
            : "=&v"(t0_), "=&v"(t1_), "=&v"(t2_), "=&v"(t3_), "=&v"(t4_),     \
              "=&v"(t5_), "=v"(t6_), "=v"(o_)                                 \
            : "v"((c)[0]), "v"((c)[1]), "v"((c)[2]), "v"((c)[3]),             \
              "v"((c)[4]), "v"((c)[5]), "v"((c)[6]), "v"((c)[7]),             \
              "v"((c)[8]), "v"((c)[9]), "v"((c)[10]), "v"((c)[11]),           \
              "v"((c)[12]), "v"((c)[13]), "v"((c)[14]), "v"((c)[15]),         \
              "v"(rm));                                                       \
        (rm) = o_;                                                            \
    } while (0)

// Issue two MFMAs into d_a, d_b (VGPR outputs, C=zc zero, D!=C).
#define MFMA2(d_a, d_b, af_, bfa, bfb, zc_)                                   \
    asm volatile(                                                             \
        "v_mfma_f32_32x32x16_f16 %0, %2, %3, %5\n\t"                          \
        "v_mfma_f32_32x32x16_f16 %1, %2, %4, %5"                              \
        : "=&v"(d_a), "=&v"(d_b)                                              \
        : "v"(af_), "v"(bfa), "v"(bfb), "v"(zc_))

__global__ __launch_bounds__(256, 4) void hausdorff(const float* __restrict__ adv,
                                                    const float* __restrict__ ori,
                                                    float* __restrict__ part,
                                                    float* __restrict__ out) {
    // Tile-planar A' slice: tile t at halfs [t*512,(t+1)*512); lane reads
    // byte lane*16 -> linear, conflict-free. +1 pad tile for last prefetch.
    __shared__ _Float16 sA[(TSLICE + 1) * 512];   // 33 KB -> 4 blocks/CU

    const int bid  = blockIdx.x;          // grid = 8 * 16 * 8 = 1024
    const int b    = bid >> 7;
    const int mc   = (bid >> 3) & (MCHUNK - 1);
    const int ns   = bid & 7;
    const int tid  = threadIdx.x;
    const int lane = tid & 63;
    const int wv   = tid >> 6;
    const int r    = lane & 31;
    const int hk   = lane >> 5;

    if (bid == 0 && tid == 0) out[0] = 0.0f;   // for reduceB's atomicAdd

    const _Float16 Z = (_Float16)0.0f, ONE = (_Float16)1.0f;

    // ---- B-fragments + aa for this wave's 4 column groups ----
    const float* advb = adv + (size_t)b * KPTS * 3;
    const int m0 = mc * CBLK + wv * 128 + r;
    half8 bf0, bf1, bf2, bf3;
    float aa0, aa1, aa2, aa3;
#pragma unroll
    for (int i = 0; i < 4; ++i) {
        const int m = m0 + 32 * i;
        float ax = advb[3 * m], ay = advb[3 * m + 1], az = advb[3 * m + 2];
        float aa = ax * ax + ay * ay + az * az;
        float tx = -2.f * ax, ty = -2.f * ay, tz = -2.f * az;
        _Float16 bx = (_Float16)tx, by = (_Float16)ty, bz = (_Float16)tz;
        _Float16 cx = (_Float16)(tx - (float)bx);
        _Float16 cy = (_Float16)(ty - (float)by);
        _Float16 cz = (_Float16)(tz - (float)bz);
        half8 h0 = {bx, by, bz, cx, cy, cz, bx, by};
        half8 h1 = {bz, ONE, ONE, Z, Z, Z, Z, Z};
        half8 bi = hk ? h1 : h0;
        if (i == 0) { bf0 = bi; aa0 = aa; }
        else if (i == 1) { bf1 = bi; aa1 = aa; }
        else if (i == 2) { bf2 = bi; aa2 = aa; }
        else { bf3 = bi; aa3 = aa; }
    }

    // ---- stage + convert this block's 1024-row slice into LDS (once) ----
    const float* orib = ori + ((size_t)b * KPTS + (size_t)ns * RBLK) * 3;
#pragma unroll
    for (int i = 0; i < 4; ++i) {
        const int rr = tid + i * 256;
        const float* op = orib + (size_t)rr * 3;
        float x = op[0], y = op[1], z = op[2];
        float oo = x * x + y * y + z * z;
        _Float16 hx = (_Float16)x, hy = (_Float16)y, hz = (_Float16)z;
        _Float16 lx = (_Float16)(x - (float)hx);
        _Float16 ly = (_Float16)(y - (float)hy);
        _Float16 lz = (_Float16)(z - (float)hz);
        _Float16 oh = (_Float16)oo;
        _Float16 ol = (_Float16)(oo - (float)oh);
        half8 a0 = {hx, hy, hz, hx, hy, hz, lx, ly};
        half8 a1 = {lz, oh, ol, Z, Z, Z, Z, Z};
        const int off = ((rr >> 5) << 9) + ((rr & 31) << 3);
        *(half8*)(&sA[off])       = a0;
        *(half8*)(&sA[off + 256]) = a1;
    }
    __syncthreads();   // the only barrier

    f32x16 zc;
#pragma unroll
    for (int i = 0; i < 16; ++i) zc[i] = 0.0f;

    float rm0 = __builtin_huge_valf(), rm1 = __builtin_huge_valf();
    float rm2 = __builtin_huge_valf(), rm3 = __builtin_huge_valf();

    const _Float16* apl = sA + lane * 8;   // lane's 16B within tile 0

    // ---- prologue: tile 0 MFMAs; nops cover RAW to first loop fold ----
    half8 af = *(const half8*)apl;
    f32x16 d0, d1, d2, d3;
    asm volatile(
        "v_mfma_f32_32x32x16_f16 %0, %4, %5, %9\n\t"
        "v_mfma_f32_32x32x16_f16 %1, %4, %6, %9\n\t"
        "v_mfma_f32_32x32x16_f16 %2, %4, %7, %9\n\t"
        "v_mfma_f32_32x32x16_f16 %3, %4, %8, %9\n\t"
        "s_nop 7\n\ts_nop 7"
        : "=&v"(d0), "=&v"(d1), "=&v"(d2), "=&v"(d3)
        : "v"(af), "v"(bf0), "v"(bf1), "v"(bf2), "v"(bf3), "v"(zc));

    // ---- pipelined main loop: fold(t-1) interleaved with MFMA(t) ----
#pragma unroll
    for (int t = 1; t < TSLICE; ++t) {
        half8 afn = *(const half8*)(apl + (size_t)t * 512);   // frag(t)
        FOLD17(rm0, d0);                  // tile t-1, covers d01(t) RAW next iter
        FOLD17(rm1, d1);
        MFMA2(d0, d1, afn, bf0, bf1, zc); // tile t
        FOLD17(rm2, d2);                  // tile t-1
        FOLD17(rm3, d3);
        MFMA2(d2, d3, afn, bf2, bf3, zc); // tile t
        af = afn;
    }

    // ---- epilogue: fold tile 31 (nops cover RAW from last MFMA2) ----
    asm volatile("s_nop 7\n\ts_nop 7" ::: );
    FOLD17(rm0, d0);
    FOLD17(rm1, d1);
    FOLD17(rm2, d2);
    FOLD17(rm3, d3);

    // complete the 32-row min (lanes l, l^32 cover complementary rows, same col)
    rm0 = fminf(rm0, __shfl_xor(rm0, 32, 64));
    rm1 = fminf(rm1, __shfl_xor(rm1, 32, 64));
    rm2 = fminf(rm2, __shfl_xor(rm2, 32, 64));
    rm3 = fminf(rm3, __shfl_xor(rm3, 32, 64));

    // plain coalesced partial stores part[ns][b][col] (no init required)
    float* p = part + ((size_t)ns * BATCH + b) * KPTS;
    if (hk == 0) {
        p[m0]      = fmaxf(rm0 + aa0, 0.0f);
        p[m0 + 32] = fmaxf(rm1 + aa1, 0.0f);
        p[m0 + 64] = fmaxf(rm2 + aa2, 0.0f);
        p[m0 + 96] = fmaxf(rm3 + aa3, 0.0f);
    }
}

// 8 blocks (one per batch), 1024 threads: min over slices, max over columns.
__global__ __launch_bounds__(1024) void reduceB(const float* __restrict__ part,
                                                const float* __restrict__ w,
                                                float* __restrict__ out) {
    const int b = blockIdx.x;
    const int tid = threadIdx.x;

    float mx = 0.0f;   // partials are clamped nonneg
#pragma unroll
    for (int h = 0; h < 2; ++h) {
        const int c4 = tid + h * 1024;
        float4 v[NSPLIT];
#pragma unroll
        for (int s = 0; s < NSPLIT; ++s)
            v[s] = *(const float4*)(part + ((size_t)s * BATCH + b) * KPTS + (size_t)c4 * 4);
        float4 mn = v[0];
#pragma unroll
        for (int s = 1; s < NSPLIT; ++s) {
            mn.x = fminf(mn.x, v[s].x); mn.y = fminf(mn.y, v[s].y);
            mn.z = fminf(mn.z, v[s].z); mn.w = fminf(mn.w, v[s].w);
        }
        mx = fmaxf(mx, fmaxf(fmaxf(mn.x, mn.y), fmaxf(mn.z, mn.w)));
    }

#pragma unroll
    for (int off = 32; off; off >>= 1)
        mx = fmaxf(mx, __shfl_xor(mx, off, 64));

    __shared__ float red[16];
    if ((tid & 63) == 0) red[tid >> 6] = mx;
    __syncthreads();
    if (tid == 0) {
        float m2 = red[0];
#pragma unroll
        for (int i = 1; i < 16; ++i) m2 = fmaxf(m2, red[i]);
        atomicAdd(out, m2 * w[b] * (1.0f / BATCH));
    }
}

extern "C" void kernel_launch(void* const* d_in, const int* in_sizes, int n_in,
                              void* d_out, int out_size, void* d_ws, size_t ws_size,
                              hipStream_t stream) {
    const float* adv = (const float*)d_in[0];   // [B, K, 3]
    const float* ori = (const float*)d_in[1];   // [B, K, 3]
    const float* w   = (const float*)d_in[2];   // [B]
    float* out = (float*)d_out;
    float* part = (float*)d_ws;                 // NSPLIT*B*K floats = 2 MB

    hausdorff<<<BATCH * MCHUNK * NSPLIT, 256, 0, stream>>>(adv, ori, part, out);
    reduceB<<<BATCH, 1024, 0, stream>>>((const float*)part, w, out);
}